// Round 9
// baseline (399.480 us; speedup 1.0000x reference)
//
#include <hip/hip_runtime.h>

#define Bq 2
#define Yq 512
#define Xq 512
#define NVOX 400000

typedef __bf16 bf16x8 __attribute__((ext_vector_type(8)));
typedef float f32x4 __attribute__((ext_vector_type(4)));
typedef float f32x16 __attribute__((ext_vector_type(16)));
typedef short s16x8 __attribute__((ext_vector_type(8)));
typedef short s16x2 __attribute__((ext_vector_type(2)));

__device__ __forceinline__ short f2bf_s(float f){
    return __builtin_bit_cast(short, static_cast<__bf16>(f));
}

__device__ __forceinline__ void atomic_pk_add_bf16(short* addr, unsigned data){
#if __has_builtin(__builtin_amdgcn_global_atomic_fadd_v2bf16)
    s16x2 v; v[0] = (short)(data & 0xffff); v[1] = (short)(data >> 16);
    __builtin_amdgcn_global_atomic_fadd_v2bf16(
        (__attribute__((address_space(1))) s16x2*)addr, v);
#else
    asm volatile("global_atomic_pk_add_bf16 %0, %1, off"
                 :: "v"(addr), "v"(data) : "memory");
#endif
}

// ---------------- weight transpose + bf16 convert ----------------
__global__ void kprep(const float* __restrict__ conv_w, const float* __restrict__ W_proj,
                      short* __restrict__ wTs, short* __restrict__ wpT){
    int tid = blockIdx.x*256 + threadIdx.x;
    if (tid < 9*128*128){
        int tap = tid >> 14; int r = tid & 16383; int co = r >> 7; int ci = r & 127;
        int g = ci >> 3, e = ci & 7;
        wTs[tap*16384 + co*128 + (((g & 8) | ((g & 7) ^ (co & 7))) << 3) + e] =
            f2bf_s(conv_w[tap*16384 + ci*128 + co]);
    }
    int e = tid - 9*128*128;
    if (e >= 0 && e < 128*192){
        int co = e / 192; int ci = e - co*192;
        wpT[e] = f2bf_s(W_proj[ci*128 + co]);
    }
}

// ---------------- per-cell multiplicity count + active mask ----------------
__global__ void kcount(const int* __restrict__ vc, unsigned* __restrict__ cnt,
                       unsigned char* __restrict__ act){
    int i = blockIdx.x*256 + threadIdx.x;
    if (i >= NVOX) return;
    const int4 c = *reinterpret_cast<const int4*>(vc + i*4);
    int cell = (c.x*Yq + c.z)*Xq + c.w;
    act[cell] = 1;
    atomicAdd(&cnt[cell], 1u);
}

// ---------------- projection + BN1 + ReLU + scatter ----------
// Singleton cells: plain store.  Multi: pk-atomic.  All-lane scatter:
// even lanes write m 0-1, odd lanes m 2-3.
__global__ void __launch_bounds__(256, 4)
kproj(const float* __restrict__ vf, const int* __restrict__ vc,
      const unsigned* __restrict__ cnt,
      const short* __restrict__ wpT, const float* __restrict__ bp,
      const float* __restrict__ g1, const float* __restrict__ be1,
      const float* __restrict__ mu1, const float* __restrict__ va1,
      short* __restrict__ dbf){
    __shared__ short A[64*200];
    __shared__ int cellsPk[64];     // (multi<<30) | P*8 + (xp&7)
    const int t = threadIdx.x;
    const int v0 = blockIdx.x * 64;

    const float4* vf4 = reinterpret_cast<const float4*>(vf);
    #pragma unroll
    for (int j = 0; j < 12; ++j){
        int i = t + j*256;
        int v = i / 48, kq = i - v*48;
        float4 x = vf4[(size_t)(v0 + v)*48 + kq];
        short4 s; s.x=f2bf_s(x.x); s.y=f2bf_s(x.y); s.z=f2bf_s(x.z); s.w=f2bf_s(x.w);
        *reinterpret_cast<short4*>(&A[v*200 + kq*4]) = s;
    }
    if (t < 64){
        int vi = v0 + t;
        int bi = vc[vi*4 + 0], yi = vc[vi*4 + 2], xi = vc[vi*4 + 3];
        unsigned cn = cnt[(bi*Yq + yi)*Xq + xi];
        int P = (bi*514 + (yi + 1))*514 + (xi + 1);
        cellsPk[t] = (P*8 + ((xi + 1) & 7)) | ((cn > 1) ? (1 << 30) : 0);
    }
    __syncthreads();

    const int w  = t >> 6;
    const int l  = t & 63;
    const int lr = l & 15;
    const int q  = l >> 4;

    const short* wp_lane = wpT + (size_t)(w*32 + lr)*192 + q*8;
    bf16x8 bb[2][6];
    #pragma unroll
    for (int n = 0; n < 2; ++n)
        #pragma unroll
        for (int kc = 0; kc < 6; ++kc)
            bb[n][kc] = *reinterpret_cast<const bf16x8*>(wp_lane + n*16*192 + kc*32);

    f32x4 acc[4][2] = {};
    #pragma unroll
    for (int kc = 0; kc < 6; ++kc){
        bf16x8 a[4];
        #pragma unroll
        for (int m = 0; m < 4; ++m)
            a[m] = *reinterpret_cast<const bf16x8*>(&A[(m*16 + lr)*200 + kc*32 + q*8]);
        #pragma unroll
        for (int m = 0; m < 4; ++m)
            #pragma unroll
            for (int n = 0; n < 2; ++n)
                acc[m][n] = __builtin_amdgcn_mfma_f32_16x16x32_bf16(a[m], bb[n][kc], acc[m][n], 0, 0, 0);
    }

    const int odd = lr & 1;
    #pragma unroll
    for (int n = 0; n < 2; ++n){
        int c = w*32 + n*16 + lr;
        float s1  = g1[c] * rsqrtf(va1[c] + 1e-5f);
        float sh1 = be1[c] + (bp[c] - mu1[c]) * s1;
        int cpair = c - odd;
        #pragma unroll
        for (int m = 0; m < 4; ++m){
            #pragma unroll
            for (int r = 0; r < 4; ++r){
                int vx = m*16 + q*4 + r;
                float val = fmaxf(fmaf(acc[m][n][r], s1, sh1), 0.f);
                float vp  = __shfl_xor(val, 1);
                if (odd == (m >> 1)){
                    int pk = cellsPk[vx];
                    int multi = pk >> 30;
                    int P = (pk & 0x3fffffff) >> 3, xp7 = pk & 7;
                    short* addr = dbf + (size_t)P*128 + (((cpair >> 3) ^ xp7) << 3) + (cpair & 7);
                    unsigned lo = odd ? (unsigned)(unsigned short)f2bf_s(vp)
                                      : (unsigned)(unsigned short)f2bf_s(val);
                    unsigned hi = odd ? (unsigned)(unsigned short)f2bf_s(val)
                                      : (unsigned)(unsigned short)f2bf_s(vp);
                    unsigned data = lo | (hi << 16);
                    if (data){
                        if (!multi) *reinterpret_cast<unsigned*>(addr) = data;
                        else atomic_pk_add_bf16(addr, data);
                    }
                }
            }
        }
    }
}

// ---------------- conv 3x3 + BN2 + ReLU + mask ----------------
// block: 4y x 64x x 128cout, 512 threads / 8 waves, wave tile 64pos x 64cout
// (m2n2), MFMA 32x32x16.  A: rows 0-3 staged in prologue, rows 4/5 staged
// inside phases 0/1 (first read at phases 6/12).  B: half-tap ping-pong.
// Phase: {vmcnt(0); barrier; sched_barrier; STAGE; reads + setprio-wrapped MFMA}.
__global__ void __launch_bounds__(512, 2)
kconv(const short* __restrict__ dbf, const short* __restrict__ wTs,
      const unsigned char* __restrict__ act, const float* __restrict__ cb,
      const float* __restrict__ g2, const float* __restrict__ be2,
      const float* __restrict__ mu2, const float* __restrict__ va2,
      float* __restrict__ out){
    __shared__ short Atile[6*1056*8];    // 101,376 B
    __shared__ short Bbuf[2][1024*8];    // 2 x 16,384 B
    const int t = threadIdx.x;
    const int bid = (blockIdx.x & 7)*256 + (blockIdx.x >> 3);
    const int b   = bid >> 10;
    const int rem = bid & 1023;
    const int y0  = (rem >> 3) << 2;
    const int x0  = (rem & 7) << 6;

    const int w   = t >> 6, l = t & 63;
    const int yy  = w >> 1, nn = w & 1;
    const int l31 = l & 31, hi = l >> 5;
    const int wbase16 = w*64*16;

    #define STAGE_B(BUF, H) do {                                              \
        const short* gb = wTs + (size_t)((H) >> 1)*16384 + ((H) & 1)*64;      \
        _Pragma("unroll")                                                     \
        for (int j = 0; j < 2; ++j){                                          \
            int S = j*512 + t;                                                \
            const short* gp = gb + (S >> 3)*128 + (S & 7)*8;                  \
            __builtin_amdgcn_global_load_lds(                                 \
                (const __attribute__((address_space(1))) void*)gp,            \
                (__attribute__((address_space(3))) void*)                    \
                    ((char*)Bbuf[BUF] + (size_t)(j*512*16) + wbase16), 16, 0, 0); \
        }                                                                     \
    } while(0)

    // prologue: B half-tap 0 + A rows 0-3 (4224 slots)
    STAGE_B(0, 0);
    #pragma unroll
    for (int j = 0; j < 9; ++j){
        int S = j*512 + t;
        if (S < 4224){
            int r = S / 1056, s = S - r*1056;
            const short* gp = dbf + ((size_t)((b*514 + (y0 + r))*514 + x0)*16 + s)*8;
            __builtin_amdgcn_global_load_lds(
                (const __attribute__((address_space(1))) void*)gp,
                (__attribute__((address_space(3))) void*)
                    ((char*)Atile + (size_t)(j*512*16) + wbase16), 16, 0, 0);
        }
    }

    f32x16 acc[2][2] = {};
    const int bReadBase = (nn*64 + l31)*64;
    const int bXor = l31 & 7;

    #pragma unroll
    for (int h = 0; h < 18; ++h){
        asm volatile("s_waitcnt vmcnt(0)" ::: "memory");
        __builtin_amdgcn_s_barrier();
        __builtin_amdgcn_sched_barrier(0);
        if (h < 17) STAGE_B((h+1) & 1, h+1);
        if (h < 2){
            const int rr = 4 + h;          // rows 4,5: first read at phases 6,12
            #pragma unroll
            for (int j = 0; j < 3; ++j){
                int S = j*512 + t;
                if (S < 1056){
                    const short* gp = dbf + ((size_t)((b*514 + (y0 + rr))*514 + x0)*16 + S)*8;
                    __builtin_amdgcn_global_load_lds(
                        (const __attribute__((address_space(1))) void*)gp,
                        (__attribute__((address_space(3))) void*)
                            ((char*)Atile + (size_t)(rr*1056 + j*512 + w*64)*16), 16, 0, 0);
                }
            }
        }
        __builtin_amdgcn_sched_barrier(0);
        const short* Bc = Bbuf[h & 1];
        const int tap = h >> 1, hh = h & 1;
        const int ky = tap / 3, kx = tap - ky*3;
        const int row = yy + ky;
        const int p0 = l31 + kx, p1 = p0 + 32;
        const int base0 = (row*1056 + p0*16)*8;
        const int base1 = (row*1056 + p1*16)*8;
        const int pk7 = p0 & 7;
        #pragma unroll
        for (int kc = 0; kc < 4; ++kc){
            const int ks  = kc*2 + hi;
            const int q   = ((hh*8 + ks) ^ pk7) << 3;
            const int qb  = (ks ^ bXor) << 3;
            bf16x8 a0 = *reinterpret_cast<const bf16x8*>(&Atile[base0 + q]);
            bf16x8 a1 = *reinterpret_cast<const bf16x8*>(&Atile[base1 + q]);
            bf16x8 b0 = *reinterpret_cast<const bf16x8*>(&Bc[bReadBase + qb]);
            bf16x8 b1 = *reinterpret_cast<const bf16x8*>(&Bc[bReadBase + 2048 + qb]);
            __builtin_amdgcn_s_setprio(1);
            acc[0][0] = __builtin_amdgcn_mfma_f32_32x32x16_bf16(a0, b0, acc[0][0], 0, 0, 0);
            acc[0][1] = __builtin_amdgcn_mfma_f32_32x32x16_bf16(a0, b1, acc[0][1], 0, 0, 0);
            acc[1][0] = __builtin_amdgcn_mfma_f32_32x32x16_bf16(a1, b0, acc[1][0], 0, 0, 0);
            acc[1][1] = __builtin_amdgcn_mfma_f32_32x32x16_bf16(a1, b1, acc[1][1], 0, 0, 0);
            __builtin_amdgcn_s_setprio(0);
        }
    }
    #undef STAGE_B

    const int yg = y0 + yy;
    const size_t rowcell = (size_t)(b*Yq + yg)*Xq + x0;
    #pragma unroll
    for (int ni = 0; ni < 2; ++ni){
        int c = nn*64 + ni*32 + l31;
        float s2  = g2[c] * rsqrtf(va2[c] + 1e-3f);
        float sh2 = be2[c] + (cb[c] - mu2[c]) * s2;
        #pragma unroll
        for (int mi = 0; mi < 2; ++mi){
            #pragma unroll
            for (int r = 0; r < 16; ++r){
                int pos = mi*32 + (r & 3) + ((r >> 2) << 3) + hi*4;
                size_t cell = rowcell + pos;
                float v = act[cell] ? fmaxf(fmaf(acc[mi][ni][r], s2, sh2), 0.f) : 0.f;
                out[cell*128 + c] = v;
            }
        }
    }
}

extern "C" void kernel_launch(void* const* d_in, const int* in_sizes, int n_in,
                              void* d_out, int out_size, void* d_ws, size_t ws_size,
                              hipStream_t stream){
    const float* vf  = (const float*)d_in[0];
    const int*   vc  = (const int*)  d_in[1];
    const float* Wp  = (const float*)d_in[2];
    const float* bp  = (const float*)d_in[3];
    const float* g1  = (const float*)d_in[4];
    const float* be1 = (const float*)d_in[5];
    const float* mu1 = (const float*)d_in[6];
    const float* va1 = (const float*)d_in[7];
    const float* cw  = (const float*)d_in[8];
    const float* cb  = (const float*)d_in[9];
    const float* g2  = (const float*)d_in[10];
    const float* be2 = (const float*)d_in[11];
    const float* mu2 = (const float*)d_in[12];
    const float* va2 = (const float*)d_in[13];
    float* out = (float*)d_out;
    char* ws = (char*)d_ws;

    // ws layout (bytes):
    //   dbf bf16 [2][514][514][128] : 135,268,352 @ 0   (padded, pre-swizzled)
    //   act  u8  [2][512][512]      :     524,288 @ 135,268,352
    //   wTs  bf16 [9][128][128]     :     294,912 @ 135,792,640  (pre-swizzled)
    //   wpT  bf16 [128][192]        :      49,152 @ 136,087,552
    //   cnt  u32 [2][512][512]      :   2,097,152 @ 136,136,704  (end 138,233,856)
    if (ws_size < 138233856ull) return;
    short* dbf = (short*)ws;
    unsigned char* act = (unsigned char*)(ws + 135268352);
    short* wTs = (short*)(ws + 135792640);
    short* wpT = (short*)(ws + 136087552);
    unsigned* cnt = (unsigned*)(ws + 136136704);

    hipMemsetAsync(dbf, 0, 135268352, stream);
    hipMemsetAsync(act, 0, 524288, stream);
    hipMemsetAsync(cnt, 0, 2097152, stream);
    kprep<<<672, 256, 0, stream>>>(cw, Wp, wTs, wpT);
    kcount<<<1563, 256, 0, stream>>>(vc, cnt, act);
    kproj<<<6250, 256, 0, stream>>>(vf, vc, cnt, wpT, bp, g1, be1, mu1, va1, dbf);
    kconv<<<2048, 512, 0, stream>>>(dbf, wTs, act, cb, g2, be2, mu2, va2, out);
}

// Round 10
// 358.464 us; speedup vs baseline: 1.1144x; 1.1144x over previous
//
#include <hip/hip_runtime.h>

#define Bq 2
#define Yq 512
#define Xq 512
#define NVOX 400000

typedef __bf16 bf16x8 __attribute__((ext_vector_type(8)));
typedef float f32x4 __attribute__((ext_vector_type(4)));
typedef float f32x16 __attribute__((ext_vector_type(16)));
typedef short s16x8 __attribute__((ext_vector_type(8)));
typedef short s16x2 __attribute__((ext_vector_type(2)));

__device__ __forceinline__ short f2bf_s(float f){
    return __builtin_bit_cast(short, static_cast<__bf16>(f));
}

__device__ __forceinline__ void atomic_pk_add_bf16(short* addr, unsigned data){
#if __has_builtin(__builtin_amdgcn_global_atomic_fadd_v2bf16)
    s16x2 v; v[0] = (short)(data & 0xffff); v[1] = (short)(data >> 16);
    __builtin_amdgcn_global_atomic_fadd_v2bf16(
        (__attribute__((address_space(1))) s16x2*)addr, v);
#else
    asm volatile("global_atomic_pk_add_bf16 %0, %1, off"
                 :: "v"(addr), "v"(data) : "memory");
#endif
}

// ---------------- weight transpose + bf16 convert ----------------
__global__ void kprep(const float* __restrict__ conv_w, const float* __restrict__ W_proj,
                      short* __restrict__ wTs, short* __restrict__ wpT){
    int tid = blockIdx.x*256 + threadIdx.x;
    if (tid < 9*128*128){
        int tap = tid >> 14; int r = tid & 16383; int co = r >> 7; int ci = r & 127;
        int g = ci >> 3, e = ci & 7;
        wTs[tap*16384 + co*128 + (((g & 8) | ((g & 7) ^ (co & 7))) << 3) + e] =
            f2bf_s(conv_w[tap*16384 + ci*128 + co]);
    }
    int e = tid - 9*128*128;
    if (e >= 0 && e < 128*192){
        int co = e / 192; int ci = e - co*192;
        wpT[e] = f2bf_s(W_proj[ci*128 + co]);
    }
}

// ---------------- per-cell multiplicity count + active mask ----------------
__global__ void kcount(const int* __restrict__ vc, unsigned* __restrict__ cnt,
                       unsigned char* __restrict__ act){
    int i = blockIdx.x*256 + threadIdx.x;
    if (i >= NVOX) return;
    const int4 c = *reinterpret_cast<const int4*>(vc + i*4);
    int cell = (c.x*Yq + c.z)*Xq + c.w;
    act[cell] = 1;
    atomicAdd(&cnt[cell], 1u);
}

// ---------------- projection + BN1 + ReLU + COALESCED scatter ----------
// Epilogue stages pairs in LDS, then each wave writes one voxel's full
// 256B channel line with 64 consecutive lanes (1-2 L2 transactions vs ~64).
__global__ void __launch_bounds__(256, 2)
kproj(const float* __restrict__ vf, const int* __restrict__ vc,
      const unsigned* __restrict__ cnt,
      const short* __restrict__ wpT, const float* __restrict__ bp,
      const float* __restrict__ g1, const float* __restrict__ be1,
      const float* __restrict__ mu1, const float* __restrict__ va1,
      short* __restrict__ dbf){
    __shared__ char smem[64*200*2];     // A (bf16 stage) ∪ st (u32 pairs)
    __shared__ int cellsPk[64];         // (multi<<30) | P*8 + (xp&7)
    short*    A  = (short*)smem;
    unsigned* st = (unsigned*)smem;     // st[vx*68 + j], j = pair index 0..63
    const int t = threadIdx.x;
    const int v0 = blockIdx.x * 64;

    const float4* vf4 = reinterpret_cast<const float4*>(vf);
    #pragma unroll
    for (int j = 0; j < 12; ++j){
        int i = t + j*256;
        int v = i / 48, kq = i - v*48;
        float4 x = vf4[(size_t)(v0 + v)*48 + kq];
        short4 s; s.x=f2bf_s(x.x); s.y=f2bf_s(x.y); s.z=f2bf_s(x.z); s.w=f2bf_s(x.w);
        *reinterpret_cast<short4*>(&A[v*200 + kq*4]) = s;
    }
    if (t < 64){
        int vi = v0 + t;
        int bi = vc[vi*4 + 0], yi = vc[vi*4 + 2], xi = vc[vi*4 + 3];
        unsigned cn = cnt[(bi*Yq + yi)*Xq + xi];
        int P = (bi*514 + (yi + 1))*514 + (xi + 1);
        cellsPk[t] = (P*8 + ((xi + 1) & 7)) | ((cn > 1) ? (1 << 30) : 0);
    }
    __syncthreads();

    const int w  = t >> 6;
    const int l  = t & 63;
    const int lr = l & 15;
    const int q  = l >> 4;

    const short* wp_lane = wpT + (size_t)(w*32 + lr)*192 + q*8;
    bf16x8 bb[2][6];
    #pragma unroll
    for (int n = 0; n < 2; ++n)
        #pragma unroll
        for (int kc = 0; kc < 6; ++kc)
            bb[n][kc] = *reinterpret_cast<const bf16x8*>(wp_lane + n*16*192 + kc*32);

    f32x4 acc[4][2] = {};
    #pragma unroll
    for (int kc = 0; kc < 6; ++kc){
        bf16x8 a[4];
        #pragma unroll
        for (int m = 0; m < 4; ++m)
            a[m] = *reinterpret_cast<const bf16x8*>(&A[(m*16 + lr)*200 + kc*32 + q*8]);
        #pragma unroll
        for (int m = 0; m < 4; ++m)
            #pragma unroll
            for (int n = 0; n < 2; ++n)
                acc[m][n] = __builtin_amdgcn_mfma_f32_16x16x32_bf16(a[m], bb[n][kc], acc[m][n], 0, 0, 0);
    }

    __syncthreads();                    // A reads done; smem becomes st
    const int odd = lr & 1;
    #pragma unroll
    for (int n = 0; n < 2; ++n){
        int c = w*32 + n*16 + lr;
        float s1  = g1[c] * rsqrtf(va1[c] + 1e-5f);
        float sh1 = be1[c] + (bp[c] - mu1[c]) * s1;
        int jj = w*16 + n*8 + (lr >> 1);
        #pragma unroll
        for (int m = 0; m < 4; ++m){
            #pragma unroll
            for (int r = 0; r < 4; ++r){
                int vx = m*16 + q*4 + r;
                float val = fmaxf(fmaf(acc[m][n][r], s1, sh1), 0.f);
                float vp  = __shfl_xor(val, 1);
                if (!odd){
                    unsigned data = (unsigned)(unsigned short)f2bf_s(val)
                                  | ((unsigned)(unsigned short)f2bf_s(vp) << 16);
                    st[vx*68 + jj] = data;
                }
            }
        }
    }
    __syncthreads();

    // scatter: wave w handles voxels w*16..w*16+15; lane j writes pair j
    unsigned* dbf_u32 = reinterpret_cast<unsigned*>(dbf);
    #pragma unroll
    for (int i = 0; i < 16; ++i){
        int vv = w*16 + i;
        int pk = cellsPk[vv];
        int multi = pk >> 30;
        int P = (pk & 0x3fffffff) >> 3, xp7 = pk & 7;
        unsigned data = st[vv*68 + l];
        size_t idx = (size_t)P*64 + (((l >> 2) ^ xp7) << 2) + (l & 3);
        if (multi){
            if (data) atomic_pk_add_bf16((short*)(dbf_u32 + idx), data);
        } else {
            dbf_u32[idx] = data;
        }
    }
}

// ---------------- conv 3x3 + BN2 + ReLU + mask ----------------
// block: 4y x 64x x 128cout, 512 threads / 8 waves, wave tile 64pos x 64cout
// (m2n2), MFMA 32x32x16.
// A: 5-row ROTATING buffer (rows 0-4 in prologue; row 5 -> phys slot 0,
//    staged at phase 6 — row 0's last read is phase 5, covered by barrier@6).
// B: half-tap 16KB x 4 buffers; at even phases stage (p+2),(p+3).
// Barrier + vmcnt(0) only at EVEN phases (9 barriers, ~1 phase drift slack).
__global__ void __launch_bounds__(512, 2)
kconv(const short* __restrict__ dbf, const short* __restrict__ wTs,
      const unsigned char* __restrict__ act, const float* __restrict__ cb,
      const float* __restrict__ g2, const float* __restrict__ be2,
      const float* __restrict__ mu2, const float* __restrict__ va2,
      float* __restrict__ out){
    __shared__ short Atile[5*1056*8];    // 84,480 B
    __shared__ short Bbuf[4][1024*8];    // 4 x 16,384 B   (total 150,016 B)
    const int t = threadIdx.x;
    const int bid = (blockIdx.x & 7)*256 + (blockIdx.x >> 3);
    const int b   = bid >> 10;
    const int rem = bid & 1023;
    const int y0  = (rem >> 3) << 2;
    const int x0  = (rem & 7) << 6;

    const int w   = t >> 6, l = t & 63;
    const int yy  = w >> 1, nn = w & 1;
    const int l31 = l & 31, hi = l >> 5;
    const int wbase16 = w*64*16;

    #define STAGE_B(BUF, H) do {                                              \
        const short* gb = wTs + (size_t)((H) >> 1)*16384 + ((H) & 1)*64;      \
        _Pragma("unroll")                                                     \
        for (int j = 0; j < 2; ++j){                                          \
            int S = j*512 + t;                                                \
            const short* gp = gb + (S >> 3)*128 + (S & 7)*8;                  \
            __builtin_amdgcn_global_load_lds(                                 \
                (const __attribute__((address_space(1))) void*)gp,            \
                (__attribute__((address_space(3))) void*)                    \
                    ((char*)Bbuf[BUF] + (size_t)(j*512*16) + wbase16), 16, 0, 0); \
        }                                                                     \
    } while(0)

    // prologue: B half-taps 0,1 + A rows 0-4 (5280 slots)
    STAGE_B(0, 0);
    STAGE_B(1, 1);
    #pragma unroll
    for (int j = 0; j < 11; ++j){
        int S = j*512 + t;
        if (S < 5280){
            int r = S / 1056, s = S - r*1056;
            const short* gp = dbf + ((size_t)((b*514 + (y0 + r))*514 + x0)*16 + s)*8;
            __builtin_amdgcn_global_load_lds(
                (const __attribute__((address_space(1))) void*)gp,
                (__attribute__((address_space(3))) void*)
                    ((char*)Atile + (size_t)(j*512*16) + wbase16), 16, 0, 0);
        }
    }

    f32x16 acc[2][2] = {};
    const int bReadBase = (nn*64 + l31)*64;
    const int bXor = l31 & 7;

    #pragma unroll
    for (int p = 0; p < 18; ++p){
        if ((p & 1) == 0){
            __builtin_amdgcn_sched_barrier(0);
            asm volatile("s_waitcnt vmcnt(0)" ::: "memory");
            __builtin_amdgcn_s_barrier();
            __builtin_amdgcn_sched_barrier(0);
            if (p + 2 < 18) STAGE_B((p+2) & 3, p+2);
            if (p + 3 < 18) STAGE_B((p+3) & 3, p+3);
            if (p == 6){
                // stage padded row 5 into phys slot 0 (first read at phase 12)
                #pragma unroll
                for (int j = 0; j < 3; ++j){
                    int S = j*512 + t;
                    if (S < 1056){
                        const short* gp = dbf + ((size_t)((b*514 + (y0 + 5))*514 + x0)*16 + S)*8;
                        __builtin_amdgcn_global_load_lds(
                            (const __attribute__((address_space(1))) void*)gp,
                            (__attribute__((address_space(3))) void*)
                                ((char*)Atile + (size_t)(j*512 + w*64)*16), 16, 0, 0);
                    }
                }
            }
            __builtin_amdgcn_sched_barrier(0);
        }
        const short* Bc = Bbuf[p & 3];
        const int tap = p >> 1, hh = p & 1;
        const int ky = tap / 3, kx = tap - ky*3;
        const int row = yy + ky;
        const int rowp = (row >= 5) ? 0 : row;       // 5-row rotation
        const int p0 = l31 + kx, p1 = p0 + 32;
        const int base0 = (rowp*1056 + p0*16)*8;
        const int base1 = (rowp*1056 + p1*16)*8;
        const int pk7 = p0 & 7;
        #pragma unroll
        for (int kc = 0; kc < 4; ++kc){
            const int ks  = kc*2 + hi;
            const int q   = ((hh*8 + ks) ^ pk7) << 3;
            const int qb  = (ks ^ bXor) << 3;
            bf16x8 a0 = *reinterpret_cast<const bf16x8*>(&Atile[base0 + q]);
            bf16x8 a1 = *reinterpret_cast<const bf16x8*>(&Atile[base1 + q]);
            bf16x8 b0 = *reinterpret_cast<const bf16x8*>(&Bc[bReadBase + qb]);
            bf16x8 b1 = *reinterpret_cast<const bf16x8*>(&Bc[bReadBase + 2048 + qb]);
            acc[0][0] = __builtin_amdgcn_mfma_f32_32x32x16_bf16(a0, b0, acc[0][0], 0, 0, 0);
            acc[0][1] = __builtin_amdgcn_mfma_f32_32x32x16_bf16(a0, b1, acc[0][1], 0, 0, 0);
            acc[1][0] = __builtin_amdgcn_mfma_f32_32x32x16_bf16(a1, b0, acc[1][0], 0, 0, 0);
            acc[1][1] = __builtin_amdgcn_mfma_f32_32x32x16_bf16(a1, b1, acc[1][1], 0, 0, 0);
        }
    }
    #undef STAGE_B

    const int yg = y0 + yy;
    const size_t rowcell = (size_t)(b*Yq + yg)*Xq + x0;
    #pragma unroll
    for (int ni = 0; ni < 2; ++ni){
        int c = nn*64 + ni*32 + l31;
        float s2  = g2[c] * rsqrtf(va2[c] + 1e-3f);
        float sh2 = be2[c] + (cb[c] - mu2[c]) * s2;
        #pragma unroll
        for (int mi = 0; mi < 2; ++mi){
            #pragma unroll
            for (int r = 0; r < 16; ++r){
                int pos = mi*32 + (r & 3) + ((r >> 2) << 3) + hi*4;
                size_t cell = rowcell + pos;
                float v = act[cell] ? fmaxf(fmaf(acc[mi][ni][r], s2, sh2), 0.f) : 0.f;
                out[cell*128 + c] = v;
            }
        }
    }
}

extern "C" void kernel_launch(void* const* d_in, const int* in_sizes, int n_in,
                              void* d_out, int out_size, void* d_ws, size_t ws_size,
                              hipStream_t stream){
    const float* vf  = (const float*)d_in[0];
    const int*   vc  = (const int*)  d_in[1];
    const float* Wp  = (const float*)d_in[2];
    const float* bp  = (const float*)d_in[3];
    const float* g1  = (const float*)d_in[4];
    const float* be1 = (const float*)d_in[5];
    const float* mu1 = (const float*)d_in[6];
    const float* va1 = (const float*)d_in[7];
    const float* cw  = (const float*)d_in[8];
    const float* cb  = (const float*)d_in[9];
    const float* g2  = (const float*)d_in[10];
    const float* be2 = (const float*)d_in[11];
    const float* mu2 = (const float*)d_in[12];
    const float* va2 = (const float*)d_in[13];
    float* out = (float*)d_out;
    char* ws = (char*)d_ws;

    // ws layout (bytes):
    //   dbf bf16 [2][514][514][128] : 135,268,352 @ 0   (padded, pre-swizzled)
    //   act  u8  [2][512][512]      :     524,288 @ 135,268,352
    //   wTs  bf16 [9][128][128]     :     294,912 @ 135,792,640  (pre-swizzled)
    //   wpT  bf16 [128][192]        :      49,152 @ 136,087,552
    //   cnt  u32 [2][512][512]      :   2,097,152 @ 136,136,704  (end 138,233,856)
    if (ws_size < 138233856ull) return;
    short* dbf = (short*)ws;
    unsigned char* act = (unsigned char*)(ws + 135268352);
    short* wTs = (short*)(ws + 135792640);
    short* wpT = (short*)(ws + 136087552);
    unsigned* cnt = (unsigned*)(ws + 136136704);

    hipMemsetAsync(dbf, 0, 135268352, stream);
    hipMemsetAsync(act, 0, 524288, stream);
    hipMemsetAsync(cnt, 0, 2097152, stream);
    kprep<<<672, 256, 0, stream>>>(cw, Wp, wTs, wpT);
    kcount<<<1563, 256, 0, stream>>>(vc, cnt, act);
    kproj<<<6250, 256, 0, stream>>>(vf, vc, cnt, wpT, bp, g1, be1, mu1, va1, dbf);
    kconv<<<2048, 512, 0, stream>>>(dbf, wTs, act, cb, g2, be2, mu2, va2, out);
}